// Round 13
// baseline (209.103 us; speedup 1.0000x reference)
//
#include <hip/hip_runtime.h>
#include <hip/hip_bf16.h>

#define NNODES 50000
#define NEDGES 800000
#define DD 128
#define EDD 32
#define BCAP 64          // bucket capacity per node (max degree ~45 for Poisson(16))

#define NBE ((NEDGES + 255) / 256)   // 3125 edge blocks in fill_pack

typedef short bfrag __attribute__((ext_vector_type(8)));   // 8 bf16 = 4 VGPRs
typedef float fx4  __attribute__((ext_vector_type(4)));    // MFMA accumulator

// packed-weight slot offsets (in units of 16B slots)
#define PW_CONV 0        // 9 kb * 8 t * 64
#define PW_Z    4608     // 8 * 8 * 64
#define PW_R    8704
#define PW_H    12800
#define PW_TOT  16896

__device__ __forceinline__ unsigned short f2bf(float f) {
    unsigned u = __float_as_uint(f);
    u += 0x7fffu + ((u >> 16) & 1u);      // round-to-nearest-even
    return (unsigned short)(u >> 16);
}
__device__ __forceinline__ float bf2f(unsigned short s) {
    return __uint_as_float(((unsigned)s) << 16);
}
__device__ __forceinline__ float fast_sigmoid(float x) {
    return 1.0f / (1.0f + __expf(-x));
}
__device__ __forceinline__ float fast_tanh(float x) {
    return 1.0f - 2.0f / (__expf(2.0f * x) + 1.0f);
}

// ---------------- fused bucket fill + weight pack ----------------
__global__ __launch_bounds__(256) void fill_pack(
    const int* __restrict__ ei, int* __restrict__ cnt, long long* __restrict__ bkt,
    const float* __restrict__ Wmsg, const float* __restrict__ Wskip,
    const float* __restrict__ Wz, const float* __restrict__ Wr,
    const float* __restrict__ Wh, bfrag* __restrict__ pW)
{
    if (blockIdx.x < NBE) {
        int e = blockIdx.x * 256 + threadIdx.x;
        if (e < NEDGES) {
            int dst = __builtin_nontemporal_load(&ei[NEDGES + e]);
            int src = __builtin_nontemporal_load(&ei[e]);
            int p = atomicAdd(&cnt[dst], 1);
            if (p < BCAP)
                bkt[((size_t)dst << 6) + p] = (long long)(unsigned)src | ((long long)e << 32);
        }
        return;
    }
    int id = (blockIdx.x - NBE) * 256 + threadIdx.x;
    if (id >= PW_TOT) return;
    const float* W = nullptr;
    int rem;
    bool conv = false;
    if (id < PW_Z)      { rem = id;           conv = true; }
    else if (id < PW_R) { rem = id - PW_Z;    W = Wz; }
    else if (id < PW_H) { rem = id - PW_R;    W = Wr; }
    else                { rem = id - PW_H;    W = Wh; }
    int kb   = rem >> 9;
    int t    = (rem >> 6) & 7;
    int lane = rem & 63;
    int col  = t * 16 + (lane & 15);
    int k0   = kb * 32 + ((lane >> 4) << 3);
    bfrag v;
    #pragma unroll
    for (int j = 0; j < 8; j++) {
        int k = k0 + j;
        float w;
        if (conv) w = (k < 160) ? Wmsg[k * DD + col] : Wskip[(k - 160) * DD + col];
        else      w = W[k * DD + col];
        v[j] = (short)f2bf(w);
    }
    pW[id] = v;
}

// ---------------- gather aggregation: one wave per node ----------------
// Bucket entries fetched on the SCALAR path (wave-uniform base via readfirstlane
// -> s_load, zero VGPR cost, no VMEM-queue dependency); x/ef gathers issue
// immediately after. Half-wave pairing: lanes 0-31 even edges, 32-63 odd.
__global__ __launch_bounds__(256) void aggregate_kernel(
    const float* __restrict__ x, const float* __restrict__ ef,
    const long long* __restrict__ bkt, const int* __restrict__ cnt,
    short* __restrict__ Sb, short* __restrict__ Tb)
{
    int n = (int)((blockIdx.x * blockDim.x + threadIdx.x) >> 6);
    n = __builtin_amdgcn_readfirstlane(n);    // wave-uniform -> SGPR
    int lane = threadIdx.x & 63;
    if (n >= NNODES) return;
    const long long* base = &bkt[(size_t)n << 6];   // SGPR base
    int i1 = cnt[n];                                // s_load
    if (i1 > BCAP) i1 = BCAP;
    const int half = lane >> 5;
    const int l32  = lane & 31;
    float4 accS = make_float4(0.0f, 0.0f, 0.0f, 0.0f);
    float accT = 0.0f;
    int i = 0;
    // main: 8 edges, bucket entries via scalar loads (uniform indices)
    for (; i + 8 <= i1; i += 8) {
        long long c[8];
        #pragma unroll
        for (int u = 0; u < 8; u++) c[u] = base[i + u];   // uniform -> s_load
        float4 v[4];
        #pragma unroll
        for (int p = 0; p < 4; p++) {
            long long cc = half ? c[2 * p + 1] : c[2 * p];
            int src = (int)(unsigned)cc;
            v[p] = *reinterpret_cast<const float4*>(&x[(size_t)src * DD + l32 * 4]);
        }
        float e[4];
        #pragma unroll
        for (int p = 0; p < 4; p++) {
            long long cc = half ? c[2 * p + 1] : c[2 * p];
            int eid = (int)(cc >> 32);
            e[p] = __builtin_nontemporal_load(&ef[(size_t)eid * EDD + l32]);
        }
        #pragma unroll
        for (int p = 0; p < 4; p++) {
            accS.x += v[p].x; accS.y += v[p].y; accS.z += v[p].z; accS.w += v[p].w;
            accT += e[p];
        }
    }
    // masked tail batch: up to 7 remaining edges, uniform clamped scalar loads
    if (i < i1) {
        long long c[8];
        #pragma unroll
        for (int u = 0; u < 8; u++) {
            int idx = i + u;
            idx = (idx < i1) ? idx : (i1 - 1);            // uniform clamp
            c[u] = base[idx];                             // s_load
        }
        bool ok[4];
        float4 v[4];
        #pragma unroll
        for (int p = 0; p < 4; p++) {
            ok[p] = (i + 2 * p + half) < i1;
            long long cc = half ? c[2 * p + 1] : c[2 * p];
            int src = (int)(unsigned)cc;
            v[p] = *reinterpret_cast<const float4*>(&x[(size_t)src * DD + l32 * 4]);
        }
        float e[4];
        #pragma unroll
        for (int p = 0; p < 4; p++) {
            long long cc = half ? c[2 * p + 1] : c[2 * p];
            int eid = (int)(cc >> 32);
            e[p] = __builtin_nontemporal_load(&ef[(size_t)eid * EDD + l32]);
        }
        #pragma unroll
        for (int p = 0; p < 4; p++) {
            accS.x += ok[p] ? v[p].x : 0.0f;
            accS.y += ok[p] ? v[p].y : 0.0f;
            accS.z += ok[p] ? v[p].z : 0.0f;
            accS.w += ok[p] ? v[p].w : 0.0f;
            accT   += ok[p] ? e[p]   : 0.0f;
        }
    }
    // combine even/odd halves
    accS.x += __shfl_xor(accS.x, 32, 64);
    accS.y += __shfl_xor(accS.y, 32, 64);
    accS.z += __shfl_xor(accS.z, 32, 64);
    accS.w += __shfl_xor(accS.w, 32, 64);
    accT   += __shfl_xor(accT,   32, 64);
    if (half == 0) {
        unsigned pk0 = ((unsigned)f2bf(accS.y) << 16) | (unsigned)f2bf(accS.x);
        unsigned pk1 = ((unsigned)f2bf(accS.w) << 16) | (unsigned)f2bf(accS.z);
        uint2 pk = make_uint2(pk0, pk1);
        *reinterpret_cast<uint2*>(&Sb[(size_t)n * DD + l32 * 4]) = pk;
        reinterpret_cast<unsigned short*>(Tb)[(size_t)n * EDD + l32] = f2bf(accT);
    }
}

// ---------------- fused MFMA node kernel: wave owns both M-tiles x 2 N-tiles ----------------
// B-fragments deduped across M: each pW slot read exactly once per block.
__global__ __launch_bounds__(256) void node_mfma(
    const float* __restrict__ x, const float* __restrict__ H,
    const short* __restrict__ Sb, const short* __restrict__ Tb,
    const bfrag* __restrict__ pW,
    const float* __restrict__ bconv, const float* __restrict__ bskip,
    const float* __restrict__ bz, const float* __restrict__ br,
    const float* __restrict__ bh,
    float* __restrict__ out)
{
    __shared__ short lclA[9 * 2 * 64 * 8];   // 18432 B
    __shared__ short lclG[4 * 2 * 64 * 8];   //  8192 B
    const int tid = threadIdx.x;
    const int n0 = blockIdx.x * 32;

    for (int s = tid; s < 1152; s += 256) {
        int kb = s >> 7, mm = (s >> 6) & 1, cb = (s >> 4) & 3, r16 = s & 15;
        int row = mm * 16 + r16, gn = n0 + row;
        int k0 = kb * 32 + cb * 8;
        bfrag v;
        if (gn < NNODES) {
            if (k0 < 128) {
                v = *(const bfrag*)&Sb[(size_t)gn * DD + k0];
            } else if (k0 < 160) {
                v = *(const bfrag*)&Tb[(size_t)gn * EDD + (k0 - 128)];
            } else {
                const float* src = &x[(size_t)gn * DD + (k0 - 160)];
                float4 p0 = *(const float4*)src;
                float4 p1 = *(const float4*)(src + 4);
                v[0] = (short)f2bf(p0.x); v[1] = (short)f2bf(p0.y);
                v[2] = (short)f2bf(p0.z); v[3] = (short)f2bf(p0.w);
                v[4] = (short)f2bf(p1.x); v[5] = (short)f2bf(p1.y);
                v[6] = (short)f2bf(p1.z); v[7] = (short)f2bf(p1.w);
            }
        } else {
            #pragma unroll
            for (int j = 0; j < 8; j++) v[j] = 0;
        }
        *(bfrag*)&lclA[((kb * 2 + mm) * 64 + (r16 | (cb << 4))) * 8] = v;
    }
    for (int s = tid; s < 512; s += 256) {
        int kb = s >> 7, mm = (s >> 6) & 1, cb = (s >> 4) & 3, r16 = s & 15;
        int row = mm * 16 + r16, gn = n0 + row;
        int c0 = kb * 32 + cb * 8;
        bfrag v;
        if (gn < NNODES) {
            const float* src = &H[(size_t)gn * DD + c0];
            float4 p0 = *(const float4*)src;
            float4 p1 = *(const float4*)(src + 4);
            v[0] = (short)f2bf(p0.x); v[1] = (short)f2bf(p0.y);
            v[2] = (short)f2bf(p0.z); v[3] = (short)f2bf(p0.w);
            v[4] = (short)f2bf(p1.x); v[5] = (short)f2bf(p1.y);
            v[6] = (short)f2bf(p1.z); v[7] = (short)f2bf(p1.w);
        } else {
            #pragma unroll
            for (int j = 0; j < 8; j++) v[j] = 0;
        }
        *(bfrag*)&lclG[((kb * 2 + mm) * 64 + (r16 | (cb << 4))) * 8] = v;
    }
    __syncthreads();

    const int w    = tid >> 6;
    const int lane = tid & 63;
    const int nt0  = w * 2;              // wave's first n-tile (owns nt0, nt0+1; both m)
    const int lc   = lane & 15;
    const int lr4  = (lane >> 4) * 4;

    // ---- conv GEMM: acc[m][t], B deduped ----
    fx4 acc[2][2];
    #pragma unroll
    for (int t = 0; t < 2; t++) {
        int c = (nt0 + t) * 16 + lc;
        float b = bconv[c] + bskip[c];
        acc[0][t] = (fx4){b, b, b, b};
        acc[1][t] = (fx4){b, b, b, b};
    }
    #pragma unroll
    for (int kb = 0; kb < 9; kb++) {
        bfrag a0 = *(const bfrag*)&lclA[((kb * 2 + 0) * 64 + lane) * 8];
        bfrag a1 = *(const bfrag*)&lclA[((kb * 2 + 1) * 64 + lane) * 8];
        #pragma unroll
        for (int t = 0; t < 2; t++) {
            bfrag b = pW[PW_CONV + (kb * 8 + nt0 + t) * 64 + lane];
            acc[0][t] = __builtin_amdgcn_mfma_f32_16x16x32_bf16(a0, b, acc[0][t], 0, 0, 0);
            acc[1][t] = __builtin_amdgcn_mfma_f32_16x16x32_bf16(a1, b, acc[1][t], 0, 0, 0);
        }
    }
    __syncthreads();

    // ---- ReLU -> h, write back as A-fragments into lclA kb0-3 ----
    #pragma unroll
    for (int m = 0; m < 2; m++)
        #pragma unroll
        for (int t = 0; t < 2; t++) {
            int c  = (nt0 + t) * 16 + lc;
            int kb = c >> 5;
            int cb = (c >> 3) & 3;
            int j  = c & 7;
            #pragma unroll
            for (int reg = 0; reg < 4; reg++) {
                int row16 = lr4 + reg;
                float hv = fmaxf(acc[m][t][reg], 0.0f);
                lclA[((kb * 2 + m) * 64 + (row16 | (cb << 4))) * 8 + j] = (short)f2bf(hv);
            }
        }
    __syncthreads();

    // ---- z, r gates: K=256, B deduped ----
    fx4 az[2][2], ar[2][2];
    #pragma unroll
    for (int t = 0; t < 2; t++) {
        int c = (nt0 + t) * 16 + lc;
        float b1 = bz[c], b2 = br[c];
        az[0][t] = (fx4){b1, b1, b1, b1};
        az[1][t] = (fx4){b1, b1, b1, b1};
        ar[0][t] = (fx4){b2, b2, b2, b2};
        ar[1][t] = (fx4){b2, b2, b2, b2};
    }
    #pragma unroll
    for (int kb = 0; kb < 8; kb++) {
        bfrag a0 = (kb < 4)
            ? *(const bfrag*)&lclA[((kb * 2 + 0) * 64 + lane) * 8]
            : *(const bfrag*)&lclG[(((kb - 4) * 2 + 0) * 64 + lane) * 8];
        bfrag a1 = (kb < 4)
            ? *(const bfrag*)&lclA[((kb * 2 + 1) * 64 + lane) * 8]
            : *(const bfrag*)&lclG[(((kb - 4) * 2 + 1) * 64 + lane) * 8];
        #pragma unroll
        for (int t = 0; t < 2; t++) {
            bfrag wz = pW[PW_Z + (kb * 8 + nt0 + t) * 64 + lane];
            bfrag wr = pW[PW_R + (kb * 8 + nt0 + t) * 64 + lane];
            az[0][t] = __builtin_amdgcn_mfma_f32_16x16x32_bf16(a0, wz, az[0][t], 0, 0, 0);
            az[1][t] = __builtin_amdgcn_mfma_f32_16x16x32_bf16(a1, wz, az[1][t], 0, 0, 0);
            ar[0][t] = __builtin_amdgcn_mfma_f32_16x16x32_bf16(a0, wr, ar[0][t], 0, 0, 0);
            ar[1][t] = __builtin_amdgcn_mfma_f32_16x16x32_bf16(a1, wr, ar[1][t], 0, 0, 0);
        }
    }

    // ---- sigmoid; read H per-lane; rH ----
    float zv[2][2][4], Hv[2][2][4], rHv[2][2][4];
    #pragma unroll
    for (int m = 0; m < 2; m++)
        #pragma unroll
        for (int t = 0; t < 2; t++) {
            int c  = (nt0 + t) * 16 + lc;
            int kb = c >> 5;
            int cb = (c >> 3) & 3;
            int j  = c & 7;
            #pragma unroll
            for (int reg = 0; reg < 4; reg++) {
                int row16 = lr4 + reg;
                zv[m][t][reg] = fast_sigmoid(az[m][t][reg]);
                float rv = fast_sigmoid(ar[m][t][reg]);
                float hH = bf2f((unsigned short)lclG[((kb * 2 + m) * 64 + (row16 | (cb << 4))) * 8 + j]);
                Hv[m][t][reg]  = hH;
                rHv[m][t][reg] = rv * hH;
            }
        }
    __syncthreads();

    // ---- overwrite lclG with rH fragments ----
    #pragma unroll
    for (int m = 0; m < 2; m++)
        #pragma unroll
        for (int t = 0; t < 2; t++) {
            int c  = (nt0 + t) * 16 + lc;
            int kb = c >> 5;
            int cb = (c >> 3) & 3;
            int j  = c & 7;
            #pragma unroll
            for (int reg = 0; reg < 4; reg++) {
                int row16 = lr4 + reg;
                lclG[((kb * 2 + m) * 64 + (row16 | (cb << 4))) * 8 + j] = (short)f2bf(rHv[m][t][reg]);
            }
        }
    __syncthreads();

    // ---- h_tilde: K=256, B deduped ----
    fx4 ah[2][2];
    #pragma unroll
    for (int t = 0; t < 2; t++) {
        int c = (nt0 + t) * 16 + lc;
        float b = bh[c];
        ah[0][t] = (fx4){b, b, b, b};
        ah[1][t] = (fx4){b, b, b, b};
    }
    #pragma unroll
    for (int kb = 0; kb < 8; kb++) {
        bfrag a0 = (kb < 4)
            ? *(const bfrag*)&lclA[((kb * 2 + 0) * 64 + lane) * 8]
            : *(const bfrag*)&lclG[(((kb - 4) * 2 + 0) * 64 + lane) * 8];
        bfrag a1 = (kb < 4)
            ? *(const bfrag*)&lclA[((kb * 2 + 1) * 64 + lane) * 8]
            : *(const bfrag*)&lclG[(((kb - 4) * 2 + 1) * 64 + lane) * 8];
        #pragma unroll
        for (int t = 0; t < 2; t++) {
            bfrag wh = pW[PW_H + (kb * 8 + nt0 + t) * 64 + lane];
            ah[0][t] = __builtin_amdgcn_mfma_f32_16x16x32_bf16(a0, wh, ah[0][t], 0, 0, 0);
            ah[1][t] = __builtin_amdgcn_mfma_f32_16x16x32_bf16(a1, wh, ah[1][t], 0, 0, 0);
        }
    }

    // ---- epilogue: out = z*H + (1-z)*tanh(ah) ----
    #pragma unroll
    for (int m = 0; m < 2; m++)
        #pragma unroll
        for (int reg = 0; reg < 4; reg++) {
            int row = m * 16 + lr4 + reg;
            int gn = n0 + row;
            if (gn < NNODES) {
                #pragma unroll
                for (int t = 0; t < 2; t++) {
                    int c = (nt0 + t) * 16 + lc;
                    float ht = fast_tanh(ah[m][t][reg]);
                    float zz = zv[m][t][reg];
                    out[(size_t)gn * DD + c] = zz * Hv[m][t][reg] + (1.0f - zz) * ht;
                }
            }
        }
}

extern "C" void kernel_launch(void* const* d_in, const int* in_sizes, int n_in,
                              void* d_out, int out_size, void* d_ws, size_t ws_size,
                              hipStream_t stream) {
    const float* x     = (const float*)d_in[0];
    const float* ef    = (const float*)d_in[1];
    const float* Hst   = (const float*)d_in[2];
    const int*   ei    = (const int*)d_in[3];
    const float* Wmsg  = (const float*)d_in[4];
    const float* bconv = (const float*)d_in[5];
    const float* Wskip = (const float*)d_in[6];
    const float* bskip = (const float*)d_in[7];
    const float* Wz    = (const float*)d_in[8];
    const float* bz    = (const float*)d_in[9];
    const float* Wr    = (const float*)d_in[10];
    const float* br    = (const float*)d_in[11];
    const float* Wh    = (const float*)d_in[12];
    const float* bh    = (const float*)d_in[13];
    float* out = (float*)d_out;

    // workspace layout (16B alignment maintained)
    bfrag* pW  = (bfrag*)d_ws;                               // 270336 B
    short* Sb  = (short*)((char*)d_ws + PW_TOT * 16);        // [N,128] bf16 12.8 MB
    short* Tb  = Sb + (size_t)NNODES * DD;                   // [N,32]  bf16  3.2 MB
    int*   cnt = (int*)(Tb + (size_t)NNODES * EDD);          // [N]
    long long* bkt = (long long*)(cnt + NNODES + 2);         // [N*64] 25.6 MB (8B-aligned)

    (void)hipMemsetAsync(cnt, 0, NNODES * sizeof(int), stream);

    int nbFP = NBE + (PW_TOT + 255) / 256;
    fill_pack<<<nbFP, 256, 0, stream>>>(ei, cnt, bkt, Wmsg, Wskip, Wz, Wr, Wh, pW);

    int nbA = (NNODES * 64 + 255) / 256;
    aggregate_kernel<<<nbA, 256, 0, stream>>>(x, ef, bkt, cnt, Sb, Tb);

    int nb2 = (NNODES + 31) / 32;
    node_mfma<<<nb2, 256, 0, stream>>>(x, Hst, Sb, Tb, pW, bconv, bskip,
                                       bz, br, bh, out);
}

// Round 14
// 167.721 us; speedup vs baseline: 1.2467x; 1.2467x over previous
//
#include <hip/hip_runtime.h>
#include <hip/hip_bf16.h>

#define NNODES 50000
#define NEDGES 800000
#define DD 128
#define EDD 32
#define BCAP 64          // bucket capacity per node (max degree ~45 for Poisson(16))

#define NBE ((NEDGES + 255) / 256)   // 3125 edge blocks in fill_pack

typedef short bfrag __attribute__((ext_vector_type(8)));   // 8 bf16 = 4 VGPRs
typedef float fx4  __attribute__((ext_vector_type(4)));    // MFMA accumulator

// packed-weight slot offsets (in units of 16B slots)
#define PW_CONV 0        // 9 kb * 8 t * 64
#define PW_Z    4608     // 8 * 8 * 64
#define PW_R    8704
#define PW_H    12800
#define PW_TOT  16896

__device__ __forceinline__ unsigned short f2bf(float f) {
    unsigned u = __float_as_uint(f);
    u += 0x7fffu + ((u >> 16) & 1u);      // round-to-nearest-even
    return (unsigned short)(u >> 16);
}
__device__ __forceinline__ float bf2f(unsigned short s) {
    return __uint_as_float(((unsigned)s) << 16);
}
__device__ __forceinline__ float fast_sigmoid(float x) {
    return 1.0f / (1.0f + __expf(-x));
}
__device__ __forceinline__ float fast_tanh(float x) {
    return 1.0f - 2.0f / (__expf(2.0f * x) + 1.0f);
}

// ---------------- fused bucket fill + weight pack ----------------
__global__ __launch_bounds__(256) void fill_pack(
    const int* __restrict__ ei, int* __restrict__ cnt, long long* __restrict__ bkt,
    const float* __restrict__ Wmsg, const float* __restrict__ Wskip,
    const float* __restrict__ Wz, const float* __restrict__ Wr,
    const float* __restrict__ Wh, bfrag* __restrict__ pW)
{
    if (blockIdx.x < NBE) {
        int e = blockIdx.x * 256 + threadIdx.x;
        if (e < NEDGES) {
            int dst = __builtin_nontemporal_load(&ei[NEDGES + e]);
            int src = __builtin_nontemporal_load(&ei[e]);
            int p = atomicAdd(&cnt[dst], 1);
            if (p < BCAP)
                bkt[((size_t)dst << 6) + p] = (long long)(unsigned)src | ((long long)e << 32);
        }
        return;
    }
    int id = (blockIdx.x - NBE) * 256 + threadIdx.x;
    if (id >= PW_TOT) return;
    const float* W = nullptr;
    int rem;
    bool conv = false;
    if (id < PW_Z)      { rem = id;           conv = true; }
    else if (id < PW_R) { rem = id - PW_Z;    W = Wz; }
    else if (id < PW_H) { rem = id - PW_R;    W = Wr; }
    else                { rem = id - PW_H;    W = Wh; }
    int kb   = rem >> 9;
    int t    = (rem >> 6) & 7;
    int lane = rem & 63;
    int col  = t * 16 + (lane & 15);
    int k0   = kb * 32 + ((lane >> 4) << 3);
    bfrag v;
    #pragma unroll
    for (int j = 0; j < 8; j++) {
        int k = k0 + j;
        float w;
        if (conv) w = (k < 160) ? Wmsg[k * DD + col] : Wskip[(k - 160) * DD + col];
        else      w = W[k * DD + col];
        v[j] = (short)f2bf(w);
    }
    pW[id] = v;
}

// ---------------- gather aggregation: one wave per node, half-wave edge pairing ----------------
// (R12-proven form: vector bkt loads, lanes 0-31 even edges / 32-63 odd edges,
//  each lane owns 4 x-cols via float4 + 1 ef-col; shfl_xor(32) combine.)
__global__ __launch_bounds__(256) void aggregate_kernel(
    const float* __restrict__ x, const float* __restrict__ ef,
    const long long* __restrict__ bkt, const int* __restrict__ cnt,
    short* __restrict__ Sb, short* __restrict__ Tb)
{
    int n = (int)((blockIdx.x * blockDim.x + threadIdx.x) >> 6);
    int lane = threadIdx.x & 63;
    if (n >= NNODES) return;
    const long long* base = &bkt[(size_t)n << 6];
    int i1 = cnt[n];
    if (i1 > BCAP) i1 = BCAP;
    const int half = lane >> 5;
    const int l32  = lane & 31;
    float4 accS = make_float4(0.0f, 0.0f, 0.0f, 0.0f);
    float accT = 0.0f;
    int i = 0;
    for (; i + 8 <= i1; i += 8) {
        long long c[4];
        #pragma unroll
        for (int p = 0; p < 4; p++) c[p] = base[i + 2 * p + half];
        float4 v[4];
        #pragma unroll
        for (int p = 0; p < 4; p++) {
            int src = (int)(unsigned)c[p];
            v[p] = *reinterpret_cast<const float4*>(&x[(size_t)src * DD + l32 * 4]);
        }
        float e[4];
        #pragma unroll
        for (int p = 0; p < 4; p++) {
            int eid = (int)(c[p] >> 32);
            e[p] = __builtin_nontemporal_load(&ef[(size_t)eid * EDD + l32]);
        }
        #pragma unroll
        for (int p = 0; p < 4; p++) {
            accS.x += v[p].x; accS.y += v[p].y; accS.z += v[p].z; accS.w += v[p].w;
            accT += e[p];
        }
    }
    if (i < i1) {
        long long c[4];
        bool ok[4];
        #pragma unroll
        for (int p = 0; p < 4; p++) {
            int idx = i + 2 * p + half;
            ok[p] = idx < i1;
            c[p] = base[ok[p] ? idx : (i1 - 1)];
        }
        float4 v[4];
        #pragma unroll
        for (int p = 0; p < 4; p++) {
            int src = (int)(unsigned)c[p];
            v[p] = *reinterpret_cast<const float4*>(&x[(size_t)src * DD + l32 * 4]);
        }
        float e[4];
        #pragma unroll
        for (int p = 0; p < 4; p++) {
            int eid = (int)(c[p] >> 32);
            e[p] = __builtin_nontemporal_load(&ef[(size_t)eid * EDD + l32]);
        }
        #pragma unroll
        for (int p = 0; p < 4; p++) {
            accS.x += ok[p] ? v[p].x : 0.0f;
            accS.y += ok[p] ? v[p].y : 0.0f;
            accS.z += ok[p] ? v[p].z : 0.0f;
            accS.w += ok[p] ? v[p].w : 0.0f;
            accT   += ok[p] ? e[p]   : 0.0f;
        }
    }
    accS.x += __shfl_xor(accS.x, 32, 64);
    accS.y += __shfl_xor(accS.y, 32, 64);
    accS.z += __shfl_xor(accS.z, 32, 64);
    accS.w += __shfl_xor(accS.w, 32, 64);
    accT   += __shfl_xor(accT,   32, 64);
    if (half == 0) {
        unsigned pk0 = ((unsigned)f2bf(accS.y) << 16) | (unsigned)f2bf(accS.x);
        unsigned pk1 = ((unsigned)f2bf(accS.w) << 16) | (unsigned)f2bf(accS.z);
        uint2 pk = make_uint2(pk0, pk1);
        *reinterpret_cast<uint2*>(&Sb[(size_t)n * DD + l32 * 4]) = pk;
        reinterpret_cast<unsigned short*>(Tb)[(size_t)n * EDD + l32] = f2bf(accT);
    }
}

// ---------------- fused MFMA node kernel: wave owns both M-tiles x 2 N-tiles ----------------
// B-fragments deduped across M: each pW slot read exactly once per block.
__global__ __launch_bounds__(256) void node_mfma(
    const float* __restrict__ x, const float* __restrict__ H,
    const short* __restrict__ Sb, const short* __restrict__ Tb,
    const bfrag* __restrict__ pW,
    const float* __restrict__ bconv, const float* __restrict__ bskip,
    const float* __restrict__ bz, const float* __restrict__ br,
    const float* __restrict__ bh,
    float* __restrict__ out)
{
    __shared__ short lclA[9 * 2 * 64 * 8];   // 18432 B
    __shared__ short lclG[4 * 2 * 64 * 8];   //  8192 B
    const int tid = threadIdx.x;
    const int n0 = blockIdx.x * 32;

    for (int s = tid; s < 1152; s += 256) {
        int kb = s >> 7, mm = (s >> 6) & 1, cb = (s >> 4) & 3, r16 = s & 15;
        int row = mm * 16 + r16, gn = n0 + row;
        int k0 = kb * 32 + cb * 8;
        bfrag v;
        if (gn < NNODES) {
            if (k0 < 128) {
                v = *(const bfrag*)&Sb[(size_t)gn * DD + k0];
            } else if (k0 < 160) {
                v = *(const bfrag*)&Tb[(size_t)gn * EDD + (k0 - 128)];
            } else {
                const float* src = &x[(size_t)gn * DD + (k0 - 160)];
                float4 p0 = *(const float4*)src;
                float4 p1 = *(const float4*)(src + 4);
                v[0] = (short)f2bf(p0.x); v[1] = (short)f2bf(p0.y);
                v[2] = (short)f2bf(p0.z); v[3] = (short)f2bf(p0.w);
                v[4] = (short)f2bf(p1.x); v[5] = (short)f2bf(p1.y);
                v[6] = (short)f2bf(p1.z); v[7] = (short)f2bf(p1.w);
            }
        } else {
            #pragma unroll
            for (int j = 0; j < 8; j++) v[j] = 0;
        }
        *(bfrag*)&lclA[((kb * 2 + mm) * 64 + (r16 | (cb << 4))) * 8] = v;
    }
    for (int s = tid; s < 512; s += 256) {
        int kb = s >> 7, mm = (s >> 6) & 1, cb = (s >> 4) & 3, r16 = s & 15;
        int row = mm * 16 + r16, gn = n0 + row;
        int c0 = kb * 32 + cb * 8;
        bfrag v;
        if (gn < NNODES) {
            const float* src = &H[(size_t)gn * DD + c0];
            float4 p0 = *(const float4*)src;
            float4 p1 = *(const float4*)(src + 4);
            v[0] = (short)f2bf(p0.x); v[1] = (short)f2bf(p0.y);
            v[2] = (short)f2bf(p0.z); v[3] = (short)f2bf(p0.w);
            v[4] = (short)f2bf(p1.x); v[5] = (short)f2bf(p1.y);
            v[6] = (short)f2bf(p1.z); v[7] = (short)f2bf(p1.w);
        } else {
            #pragma unroll
            for (int j = 0; j < 8; j++) v[j] = 0;
        }
        *(bfrag*)&lclG[((kb * 2 + mm) * 64 + (r16 | (cb << 4))) * 8] = v;
    }
    __syncthreads();

    const int w    = tid >> 6;
    const int lane = tid & 63;
    const int nt0  = w * 2;              // wave's first n-tile (owns nt0, nt0+1; both m)
    const int lc   = lane & 15;
    const int lr4  = (lane >> 4) * 4;

    // ---- conv GEMM: acc[m][t], B deduped ----
    fx4 acc[2][2];
    #pragma unroll
    for (int t = 0; t < 2; t++) {
        int c = (nt0 + t) * 16 + lc;
        float b = bconv[c] + bskip[c];
        acc[0][t] = (fx4){b, b, b, b};
        acc[1][t] = (fx4){b, b, b, b};
    }
    #pragma unroll
    for (int kb = 0; kb < 9; kb++) {
        bfrag a0 = *(const bfrag*)&lclA[((kb * 2 + 0) * 64 + lane) * 8];
        bfrag a1 = *(const bfrag*)&lclA[((kb * 2 + 1) * 64 + lane) * 8];
        #pragma unroll
        for (int t = 0; t < 2; t++) {
            bfrag b = pW[PW_CONV + (kb * 8 + nt0 + t) * 64 + lane];
            acc[0][t] = __builtin_amdgcn_mfma_f32_16x16x32_bf16(a0, b, acc[0][t], 0, 0, 0);
            acc[1][t] = __builtin_amdgcn_mfma_f32_16x16x32_bf16(a1, b, acc[1][t], 0, 0, 0);
        }
    }
    __syncthreads();

    // ---- ReLU -> h, write back as A-fragments into lclA kb0-3 ----
    #pragma unroll
    for (int m = 0; m < 2; m++)
        #pragma unroll
        for (int t = 0; t < 2; t++) {
            int c  = (nt0 + t) * 16 + lc;
            int kb = c >> 5;
            int cb = (c >> 3) & 3;
            int j  = c & 7;
            #pragma unroll
            for (int reg = 0; reg < 4; reg++) {
                int row16 = lr4 + reg;
                float hv = fmaxf(acc[m][t][reg], 0.0f);
                lclA[((kb * 2 + m) * 64 + (row16 | (cb << 4))) * 8 + j] = (short)f2bf(hv);
            }
        }
    __syncthreads();

    // ---- z, r gates: K=256, B deduped ----
    fx4 az[2][2], ar[2][2];
    #pragma unroll
    for (int t = 0; t < 2; t++) {
        int c = (nt0 + t) * 16 + lc;
        float b1 = bz[c], b2 = br[c];
        az[0][t] = (fx4){b1, b1, b1, b1};
        az[1][t] = (fx4){b1, b1, b1, b1};
        ar[0][t] = (fx4){b2, b2, b2, b2};
        ar[1][t] = (fx4){b2, b2, b2, b2};
    }
    #pragma unroll
    for (int kb = 0; kb < 8; kb++) {
        bfrag a0 = (kb < 4)
            ? *(const bfrag*)&lclA[((kb * 2 + 0) * 64 + lane) * 8]
            : *(const bfrag*)&lclG[(((kb - 4) * 2 + 0) * 64 + lane) * 8];
        bfrag a1 = (kb < 4)
            ? *(const bfrag*)&lclA[((kb * 2 + 1) * 64 + lane) * 8]
            : *(const bfrag*)&lclG[(((kb - 4) * 2 + 1) * 64 + lane) * 8];
        #pragma unroll
        for (int t = 0; t < 2; t++) {
            bfrag wz = pW[PW_Z + (kb * 8 + nt0 + t) * 64 + lane];
            bfrag wr = pW[PW_R + (kb * 8 + nt0 + t) * 64 + lane];
            az[0][t] = __builtin_amdgcn_mfma_f32_16x16x32_bf16(a0, wz, az[0][t], 0, 0, 0);
            az[1][t] = __builtin_amdgcn_mfma_f32_16x16x32_bf16(a1, wz, az[1][t], 0, 0, 0);
            ar[0][t] = __builtin_amdgcn_mfma_f32_16x16x32_bf16(a0, wr, ar[0][t], 0, 0, 0);
            ar[1][t] = __builtin_amdgcn_mfma_f32_16x16x32_bf16(a1, wr, ar[1][t], 0, 0, 0);
        }
    }

    // ---- sigmoid; read H per-lane; rH ----
    float zv[2][2][4], Hv[2][2][4], rHv[2][2][4];
    #pragma unroll
    for (int m = 0; m < 2; m++)
        #pragma unroll
        for (int t = 0; t < 2; t++) {
            int c  = (nt0 + t) * 16 + lc;
            int kb = c >> 5;
            int cb = (c >> 3) & 3;
            int j  = c & 7;
            #pragma unroll
            for (int reg = 0; reg < 4; reg++) {
                int row16 = lr4 + reg;
                zv[m][t][reg] = fast_sigmoid(az[m][t][reg]);
                float rv = fast_sigmoid(ar[m][t][reg]);
                float hH = bf2f((unsigned short)lclG[((kb * 2 + m) * 64 + (row16 | (cb << 4))) * 8 + j]);
                Hv[m][t][reg]  = hH;
                rHv[m][t][reg] = rv * hH;
            }
        }
    __syncthreads();

    // ---- overwrite lclG with rH fragments ----
    #pragma unroll
    for (int m = 0; m < 2; m++)
        #pragma unroll
        for (int t = 0; t < 2; t++) {
            int c  = (nt0 + t) * 16 + lc;
            int kb = c >> 5;
            int cb = (c >> 3) & 3;
            int j  = c & 7;
            #pragma unroll
            for (int reg = 0; reg < 4; reg++) {
                int row16 = lr4 + reg;
                lclG[((kb * 2 + m) * 64 + (row16 | (cb << 4))) * 8 + j] = (short)f2bf(rHv[m][t][reg]);
            }
        }
    __syncthreads();

    // ---- h_tilde: K=256, B deduped ----
    fx4 ah[2][2];
    #pragma unroll
    for (int t = 0; t < 2; t++) {
        int c = (nt0 + t) * 16 + lc;
        float b = bh[c];
        ah[0][t] = (fx4){b, b, b, b};
        ah[1][t] = (fx4){b, b, b, b};
    }
    #pragma unroll
    for (int kb = 0; kb < 8; kb++) {
        bfrag a0 = (kb < 4)
            ? *(const bfrag*)&lclA[((kb * 2 + 0) * 64 + lane) * 8]
            : *(const bfrag*)&lclG[(((kb - 4) * 2 + 0) * 64 + lane) * 8];
        bfrag a1 = (kb < 4)
            ? *(const bfrag*)&lclA[((kb * 2 + 1) * 64 + lane) * 8]
            : *(const bfrag*)&lclG[(((kb - 4) * 2 + 1) * 64 + lane) * 8];
        #pragma unroll
        for (int t = 0; t < 2; t++) {
            bfrag wh = pW[PW_H + (kb * 8 + nt0 + t) * 64 + lane];
            ah[0][t] = __builtin_amdgcn_mfma_f32_16x16x32_bf16(a0, wh, ah[0][t], 0, 0, 0);
            ah[1][t] = __builtin_amdgcn_mfma_f32_16x16x32_bf16(a1, wh, ah[1][t], 0, 0, 0);
        }
    }

    // ---- epilogue: out = z*H + (1-z)*tanh(ah) ----
    #pragma unroll
    for (int m = 0; m < 2; m++)
        #pragma unroll
        for (int reg = 0; reg < 4; reg++) {
            int row = m * 16 + lr4 + reg;
            int gn = n0 + row;
            if (gn < NNODES) {
                #pragma unroll
                for (int t = 0; t < 2; t++) {
                    int c = (nt0 + t) * 16 + lc;
                    float ht = fast_tanh(ah[m][t][reg]);
                    float zz = zv[m][t][reg];
                    out[(size_t)gn * DD + c] = zz * Hv[m][t][reg] + (1.0f - zz) * ht;
                }
            }
        }
}

extern "C" void kernel_launch(void* const* d_in, const int* in_sizes, int n_in,
                              void* d_out, int out_size, void* d_ws, size_t ws_size,
                              hipStream_t stream) {
    const float* x     = (const float*)d_in[0];
    const float* ef    = (const float*)d_in[1];
    const float* Hst   = (const float*)d_in[2];
    const int*   ei    = (const int*)d_in[3];
    const float* Wmsg  = (const float*)d_in[4];
    const float* bconv = (const float*)d_in[5];
    const float* Wskip = (const float*)d_in[6];
    const float* bskip = (const float*)d_in[7];
    const float* Wz    = (const float*)d_in[8];
    const float* bz    = (const float*)d_in[9];
    const float* Wr    = (const float*)d_in[10];
    const float* br    = (const float*)d_in[11];
    const float* Wh    = (const float*)d_in[12];
    const float* bh    = (const float*)d_in[13];
    float* out = (float*)d_out;

    // workspace layout (16B alignment maintained)
    bfrag* pW  = (bfrag*)d_ws;                               // 270336 B
    short* Sb  = (short*)((char*)d_ws + PW_TOT * 16);        // [N,128] bf16 12.8 MB
    short* Tb  = Sb + (size_t)NNODES * DD;                   // [N,32]  bf16  3.2 MB
    int*   cnt = (int*)(Tb + (size_t)NNODES * EDD);          // [N]
    long long* bkt = (long long*)(cnt + NNODES + 2);         // [N*64] 25.6 MB (8B-aligned)

    (void)hipMemsetAsync(cnt, 0, NNODES * sizeof(int), stream);

    int nbFP = NBE + (PW_TOT + 255) / 256;
    fill_pack<<<nbFP, 256, 0, stream>>>(ei, cnt, bkt, Wmsg, Wskip, Wz, Wr, Wh, pW);

    int nbA = (NNODES * 64 + 255) / 256;
    aggregate_kernel<<<nbA, 256, 0, stream>>>(x, ef, bkt, cnt, Sb, Tb);

    int nb2 = (NNODES + 31) / 32;
    node_mfma<<<nb2, 256, 0, stream>>>(x, Hst, Sb, Tb, pW, bconv, bskip,
                                       bz, br, bh, out);
}